// Round 1
// baseline (129.475 us; speedup 1.0000x reference)
//
#include <hip/hip_runtime.h>
#include <hip/hip_bf16.h>
#include <hip/hip_fp16.h>

// ---------------- constants (problem is fixed-shape) ----------------
#define SEQ   2048
#define DIM   1024
#define NHEAD 16
#define HD    64
// grid (8,16,16), window (3,5,5) -> half windows 1,2,2

typedef _Float16 half8 __attribute__((ext_vector_type(8)));
typedef _Float16 half4 __attribute__((ext_vector_type(4)));
typedef float    floatx4 __attribute__((ext_vector_type(4)));

// ---------------- 1. convert fp32 -> fp16 (vectorized) ----------------
__global__ void cvt_f32_f16(const float* __restrict__ in, _Float16* __restrict__ out) {
    int i = blockIdx.x * blockDim.x + threadIdx.x;
    int base = i * 4;
    float4 v = *reinterpret_cast<const float4*>(in + base);
    half4 o = { (_Float16)v.x, (_Float16)v.y, (_Float16)v.z, (_Float16)v.w };
    *reinterpret_cast<half4*>(out + base) = o;
}

// ---------------- 2. transpose + convert weights: T[n][k] = W[k][n] ----------------
__global__ void transpose_cvt(const float* __restrict__ W0, const float* __restrict__ W1,
                              const float* __restrict__ W2, const float* __restrict__ W3,
                              _Float16* __restrict__ T) {
    int z = blockIdx.z;
    const float* W = (z == 0) ? W0 : (z == 1) ? W1 : (z == 2) ? W2 : W3;
    _Float16* Tz = T + (size_t)z * (DIM * DIM);
    __shared__ float tile[32][33];
    int bx = blockIdx.x * 32;   // n-dim base
    int by = blockIdx.y * 32;   // k-dim base
    int tx = threadIdx.x, ty = threadIdx.y;
    #pragma unroll
    for (int i = 0; i < 32; i += 8)
        tile[ty + i][tx] = W[(size_t)(by + ty + i) * DIM + bx + tx];
    __syncthreads();
    #pragma unroll
    for (int i = 0; i < 32; i += 8)
        Tz[(size_t)(bx + ty + i) * DIM + by + tx] = (_Float16)tile[tx][ty + i];
}

// ---------------- 3/5. MFMA GEMM: C[M][N] = A[M][K] * Bt[N][K]^T ----------------
// M=2048, N=1024, K=1024. 128x128 tile, BK=32, 256 threads = 4 waves (2x2),
// each wave 64x64 = 4x4 fragments of mfma_f32_16x16x32_f16.
// MODE 0: write f16 QKV layout [head][s][64], z selects {Wq,Wk,Wv} and {Q,K,V}.
// MODE 1: write f32 + bias to out.
template <int MODE>
__global__ __launch_bounds__(256) void gemm128(
        const _Float16* __restrict__ A, const _Float16* __restrict__ Bt,
        _Float16* __restrict__ outF16, float* __restrict__ outF32,
        const float* __restrict__ bias) {
    int tm = blockIdx.x;           // 16 tiles of M
    int tn = blockIdx.y;           // 8 tiles of N
    int z  = blockIdx.z;
    const _Float16* Bz = Bt + (size_t)z * (DIM * DIM);
    _Float16* Oz = (MODE == 0) ? (outF16 + (size_t)z * (SEQ * DIM)) : nullptr;

    int tid = threadIdx.x;
    int lane = tid & 63;
    int wid  = tid >> 6;
    int wr = wid >> 1, wc = wid & 1;

    __shared__ _Float16 As[128][40];  // +8 pad: row stride 80B (16B-aligned, bank-spread)
    __shared__ _Float16 Bs[128][40];

    floatx4 acc[4][4] = {};

    int r16 = lane & 15;
    int kk  = (lane >> 4) * 8;

    for (int k0 = 0; k0 < DIM; k0 += 32) {
        #pragma unroll
        for (int i = 0; i < 2; i++) {
            int e = (tid + i * 256) * 8;
            int row = e >> 5, col = e & 31;
            uint4 va = *reinterpret_cast<const uint4*>(A  + (size_t)(tm * 128 + row) * DIM + k0 + col);
            *reinterpret_cast<uint4*>(&As[row][col]) = va;
            uint4 vb = *reinterpret_cast<const uint4*>(Bz + (size_t)(tn * 128 + row) * DIM + k0 + col);
            *reinterpret_cast<uint4*>(&Bs[row][col]) = vb;
        }
        __syncthreads();
        half8 a[4], b[4];
        #pragma unroll
        for (int m = 0; m < 4; m++) a[m] = *reinterpret_cast<half8*>(&As[wr * 64 + m * 16 + r16][kk]);
        #pragma unroll
        for (int n = 0; n < 4; n++) b[n] = *reinterpret_cast<half8*>(&Bs[wc * 64 + n * 16 + r16][kk]);
        #pragma unroll
        for (int m = 0; m < 4; m++)
            #pragma unroll
            for (int n = 0; n < 4; n++)
                acc[m][n] = __builtin_amdgcn_mfma_f32_16x16x32_f16(a[m], b[n], acc[m][n], 0, 0, 0);
        __syncthreads();
    }

    // epilogue: C/D layout col=lane&15, row=(lane>>4)*4+r  [verified m89/m91]
    #pragma unroll
    for (int m = 0; m < 4; m++) {
        #pragma unroll
        for (int n = 0; n < 4; n++) {
            #pragma unroll
            for (int r = 0; r < 4; r++) {
                int row = tm * 128 + wr * 64 + m * 16 + (lane >> 4) * 4 + r;
                int col = tn * 128 + wc * 64 + n * 16 + (lane & 15);
                float v = acc[m][n][r];
                if (MODE == 0) {
                    int head = col >> 6;
                    Oz[(size_t)head * (SEQ * HD) + (size_t)row * HD + (col & 63)] = (_Float16)v;
                } else {
                    outF32[(size_t)row * DIM + col] = v + bias[col];
                }
            }
        }
    }
}

// ---------------- 4. windowed attention: 1 wave per (query, head) ----------------
// q at (f,h,w): keys in clamped box |df|<=1, |dh|<=2, |dw|<=2  (<=75 keys)
__global__ __launch_bounds__(256) void attn_win(
        const _Float16* __restrict__ Q, const _Float16* __restrict__ K,
        const _Float16* __restrict__ V, _Float16* __restrict__ AO) {
    __shared__ float qsh[4][64];
    __shared__ float psh[4][128];
    __shared__ int   kssh[4][128];

    int wid  = threadIdx.x >> 6;
    int lane = threadIdx.x & 63;
    int g    = blockIdx.x * 4 + wid;     // 0..32767
    int head = g >> 11;
    int qs   = g & 2047;

    const _Float16* Qh = Q + (size_t)head * (SEQ * HD);
    const _Float16* Kh = K + (size_t)head * (SEQ * HD);
    const _Float16* Vh = V + (size_t)head * (SEQ * HD);

    qsh[wid][lane] = (float)Qh[(size_t)qs * HD + lane] * 0.125f;  // 1/sqrt(64)
    __syncthreads();

    int f = qs >> 8, h = (qs >> 4) & 15, w = qs & 15;
    int f0 = max(f - 1, 0), f1 = min(f + 1, 7);
    int h0 = max(h - 2, 0), h1 = min(h + 2, 15);
    int w0 = max(w - 2, 0), w1 = min(w + 2, 15);
    int nh = h1 - h0 + 1, nw = w1 - w0 + 1, nf = f1 - f0 + 1;
    int nhw = nh * nw, nk = nf * nhw;

    float s[2]; int ks[2];
    #pragma unroll
    for (int t = 0; t < 2; t++) {
        int j = lane + t * 64;
        s[t] = -1e30f; ks[t] = 0;
        if (j < nk) {
            int fj  = f0 + j / nhw;
            int rem = j - (j / nhw) * nhw;
            int hj  = h0 + rem / nw;
            int wj  = w0 + rem - (rem / nw) * nw;
            int kp  = (fj << 8) + (hj << 4) + wj;
            ks[t] = kp;
            const half8* kvp = reinterpret_cast<const half8*>(Kh + (size_t)kp * HD);
            float acc = 0.f;
            #pragma unroll
            for (int dd = 0; dd < 8; dd++) {
                half8 kv = kvp[dd];
                #pragma unroll
                for (int i = 0; i < 8; i++) acc += qsh[wid][dd * 8 + i] * (float)kv[i];
            }
            s[t] = acc;
        }
    }

    float m = fmaxf(s[0], s[1]);
    #pragma unroll
    for (int off = 1; off < 64; off <<= 1) m = fmaxf(m, __shfl_xor(m, off));
    float p0 = (lane      < nk) ? __expf(s[0] - m) : 0.f;
    float p1 = (lane + 64 < nk) ? __expf(s[1] - m) : 0.f;
    float sum = p0 + p1;
    #pragma unroll
    for (int off = 1; off < 64; off <<= 1) sum += __shfl_xor(sum, off);
    float inv = 1.f / sum;

    psh[wid][lane]      = p0 * inv;
    psh[wid][lane + 64] = p1 * inv;
    kssh[wid][lane]      = ks[0];
    kssh[wid][lane + 64] = ks[1];
    __syncthreads();

    float acc = 0.f;
    for (int j = 0; j < nk; j++) {
        float p  = psh[wid][j];
        int   kp = kssh[wid][j];
        acc += p * (float)Vh[(size_t)kp * HD + lane];   // coalesced over lanes
    }
    AO[(size_t)qs * DIM + head * HD + lane] = (_Float16)acc;
}

// ---------------- launch ----------------
extern "C" void kernel_launch(void* const* d_in, const int* in_sizes, int n_in,
                              void* d_out, int out_size, void* d_ws, size_t ws_size,
                              hipStream_t stream) {
    const float* H  = (const float*)d_in[0];
    const float* Wq = (const float*)d_in[1];
    const float* Wk = (const float*)d_in[2];
    const float* Wv = (const float*)d_in[3];
    const float* Wo = (const float*)d_in[4];
    const float* bo = (const float*)d_in[5];

    char* ws = (char*)d_ws;
    // layout (bytes): Hf16 [0,4M) | Wt x4 [4M,12M) | QKV x3 [12M,24M) | AO [24M,28M)
    _Float16* Hf  = (_Float16*)(ws);
    _Float16* Wt  = (_Float16*)(ws + (4u  << 20));
    _Float16* QKV = (_Float16*)(ws + (12u << 20));
    _Float16* AO  = (_Float16*)(ws + (24u << 20));

    _Float16* Qp = QKV;
    _Float16* Kp = QKV + (size_t)(SEQ * DIM);
    _Float16* Vp = QKV + (size_t)2 * (SEQ * DIM);

    // 1. H -> f16 (2M elems, 4/thread)
    cvt_f32_f16<<<(SEQ * DIM) / (256 * 4), 256, 0, stream>>>(H, Hf);

    // 2. weights -> transposed f16
    transpose_cvt<<<dim3(32, 32, 4), dim3(32, 8), 0, stream>>>(Wq, Wk, Wv, Wo, Wt);

    // 3. QKV projections (z = 0,1,2)
    gemm128<0><<<dim3(16, 8, 3), 256, 0, stream>>>(Hf, Wt, QKV, nullptr, nullptr);

    // 4. windowed attention (32768 query-head waves, 4 per block)
    attn_win<<<(SEQ * NHEAD) / 4, 256, 0, stream>>>(Qp, Kp, Vp, AO);

    // 5. output projection + bias
    gemm128<1><<<dim3(16, 8, 1), 256, 0, stream>>>(AO, Wt + (size_t)3 * (DIM * DIM), nullptr,
                                                   (float*)d_out, bo);
}

// Round 2
// 113.211 us; speedup vs baseline: 1.1437x; 1.1437x over previous
//
#include <hip/hip_runtime.h>
#include <hip/hip_bf16.h>
#include <hip/hip_fp16.h>

// ---------------- constants (problem is fixed-shape) ----------------
#define SEQ   2048
#define DIM   1024
#define NHEAD 16
#define HD    64
// grid (8,16,16), window (3,5,5) -> half windows 1,2,2
#define QSCALE 0.18033688011112042f   // (1/sqrt(64)) * log2(e), folded into Q

typedef _Float16 half8 __attribute__((ext_vector_type(8)));
typedef _Float16 half4 __attribute__((ext_vector_type(4)));
typedef float    floatx4 __attribute__((ext_vector_type(4)));

// ---------------- 1. convert fp32 -> fp16 (vectorized) ----------------
__global__ void cvt_f32_f16(const float* __restrict__ in, _Float16* __restrict__ out) {
    int i = blockIdx.x * blockDim.x + threadIdx.x;
    int base = i * 4;
    float4 v = *reinterpret_cast<const float4*>(in + base);
    half4 o = { (_Float16)v.x, (_Float16)v.y, (_Float16)v.z, (_Float16)v.w };
    *reinterpret_cast<half4*>(out + base) = o;
}

// ---------------- 2. transpose + convert weights: T[n][k] = W[k][n] ----------------
__global__ void transpose_cvt(const float* __restrict__ W0, const float* __restrict__ W1,
                              const float* __restrict__ W2, const float* __restrict__ W3,
                              _Float16* __restrict__ T) {
    int z = blockIdx.z;
    const float* W = (z == 0) ? W0 : (z == 1) ? W1 : (z == 2) ? W2 : W3;
    _Float16* Tz = T + (size_t)z * (DIM * DIM);
    __shared__ float tile[32][33];
    int bx = blockIdx.x * 32;   // n-dim base
    int by = blockIdx.y * 32;   // k-dim base
    int tx = threadIdx.x, ty = threadIdx.y;
    #pragma unroll
    for (int i = 0; i < 32; i += 8)
        tile[ty + i][tx] = W[(size_t)(by + ty + i) * DIM + bx + tx];
    __syncthreads();
    #pragma unroll
    for (int i = 0; i < 32; i += 8)
        Tz[(size_t)(bx + ty + i) * DIM + by + tx] = (_Float16)tile[tx][ty + i];
}

// ---------------- 3/5. MFMA GEMM: C[M][N] = A[M][K] * Bt[N][K]^T ----------------
// 128x128 tile, BK=32, 256 threads = 4 waves (2x2), wave = 4x4 frags of 16x16x32.
// MODE 0: write f16 per-head [head][s][64]; z selects {Wq,Wk}; z==0 scaled by QSCALE.
// MODE 1: write f32 + bias to out.
// MODE 2: write f16 row-major C[M][N]  (used for V^T: A=Wv^T, Bt=H -> C = V^T [1024][2048])
template <int MODE>
__global__ __launch_bounds__(256) void gemm128(
        const _Float16* __restrict__ A, const _Float16* __restrict__ Bt,
        _Float16* __restrict__ outF16, float* __restrict__ outF32,
        const float* __restrict__ bias, int Ncols) {
    int tm = blockIdx.x;
    int tn = blockIdx.y;
    int z  = blockIdx.z;
    const _Float16* Bz = Bt + (size_t)z * (DIM * DIM);
    _Float16* Oz = (MODE == 0) ? (outF16 + (size_t)z * (SEQ * DIM)) : outF16;
    float qs = (MODE == 0 && z == 0) ? QSCALE : 1.0f;

    int tid = threadIdx.x;
    int lane = tid & 63;
    int wid  = tid >> 6;
    int wr = wid >> 1, wc = wid & 1;

    __shared__ _Float16 As[128][40];
    __shared__ _Float16 Bs[128][40];

    floatx4 acc[4][4] = {};

    int r16 = lane & 15;
    int kk  = (lane >> 4) * 8;

    for (int k0 = 0; k0 < DIM; k0 += 32) {
        #pragma unroll
        for (int i = 0; i < 2; i++) {
            int e = (tid + i * 256) * 8;
            int row = e >> 5, col = e & 31;
            uint4 va = *reinterpret_cast<const uint4*>(A  + (size_t)(tm * 128 + row) * DIM + k0 + col);
            *reinterpret_cast<uint4*>(&As[row][col]) = va;
            uint4 vb = *reinterpret_cast<const uint4*>(Bz + (size_t)(tn * 128 + row) * DIM + k0 + col);
            *reinterpret_cast<uint4*>(&Bs[row][col]) = vb;
        }
        __syncthreads();
        half8 a[4], b[4];
        #pragma unroll
        for (int m = 0; m < 4; m++) a[m] = *reinterpret_cast<half8*>(&As[wr * 64 + m * 16 + r16][kk]);
        #pragma unroll
        for (int n = 0; n < 4; n++) b[n] = *reinterpret_cast<half8*>(&Bs[wc * 64 + n * 16 + r16][kk]);
        #pragma unroll
        for (int m = 0; m < 4; m++)
            #pragma unroll
            for (int n = 0; n < 4; n++)
                acc[m][n] = __builtin_amdgcn_mfma_f32_16x16x32_f16(a[m], b[n], acc[m][n], 0, 0, 0);
        __syncthreads();
    }

    // epilogue: C/D layout col=lane&15, row=(lane>>4)*4+r
    #pragma unroll
    for (int m = 0; m < 4; m++) {
        #pragma unroll
        for (int n = 0; n < 4; n++) {
            #pragma unroll
            for (int r = 0; r < 4; r++) {
                int row = tm * 128 + wr * 64 + m * 16 + (lane >> 4) * 4 + r;
                int col = tn * 128 + wc * 64 + n * 16 + (lane & 15);
                float v = acc[m][n][r];
                if (MODE == 0) {
                    int head = col >> 6;
                    Oz[(size_t)head * (SEQ * HD) + (size_t)row * HD + (col & 63)] = (_Float16)(v * qs);
                } else if (MODE == 2) {
                    Oz[(size_t)row * Ncols + col] = (_Float16)v;
                } else {
                    outF32[(size_t)row * DIM + col] = v + bias[col];
                }
            }
        }
    }
}

// ---------------- 4. MFMA windowed attention: 1 wave per (head, f, h) row ----------------
// 16 queries (one w-row). Keys: 3 f-chunks x 6 h-rows x 16 w = 288, contiguous per chunk.
// Q pre-scaled by QSCALE at GEMM; softmax = exp2 with no max-sub; normalize at epilogue.
__global__ __launch_bounds__(64) void attn_mfma(
        const _Float16* __restrict__ Q,    // [16][2048][64] (scaled)
        const _Float16* __restrict__ K,    // [16][2048][64]
        const _Float16* __restrict__ Vt,   // [16][64][2048]
        _Float16* __restrict__ AO) {       // [2048][1024]
    __shared__ char P_lds[16 * 640];       // P[16 q][288 key] f16, 640B row, XOR-swizzled

    int lane = threadIdx.x;
    int g    = lane >> 4;      // 0..3
    int ql   = lane & 15;

    int bid  = blockIdx.x;
    int rid  = bid & 127;      // (f,h)
    int head = bid >> 7;
    int f    = rid >> 4;
    int hq   = rid & 15;
    int s0   = rid << 4;

    const _Float16* Qh = Q  + (size_t)head * (SEQ * HD);
    const _Float16* Kh = K  + (size_t)head * (SEQ * HD);
    const _Float16* Vh = Vt + (size_t)head * (HD * SEQ);

    int f_start = min(max(f - 1, 0), 5);
    int h_start = min(max(hq - 2, 0), 10);

    // per-lane w-mask: key w' = g*4+r, query w = ql
    bool wm[4];
    #pragma unroll
    for (int r = 0; r < 4; r++) {
        int wp = g * 4 + r;
        wm[r] = (wp - ql <= 2) && (ql - wp <= 2);
    }

    // Q B-frags (2 k-steps over d=64)
    half8 qf[2];
    #pragma unroll
    for (int ks = 0; ks < 2; ks++)
        qf[ks] = *reinterpret_cast<const half8*>(Qh + (size_t)(s0 + ql) * HD + ks * 32 + g * 8);

    float lsum = 0.f;
    int swz = (ql & 7) << 4;

    #pragma unroll
    for (int fi = 0; fi < 3; fi++) {
        int fp = f_start + fi;
        bool fok = (fp - f <= 1) && (f - fp <= 1);
        int sbase = fp * 256 + h_start * 16;
        const _Float16* Kc = Kh + (size_t)sbase * HD;

        floatx4 sacc[6];
        #pragma unroll
        for (int j = 0; j < 6; j++) sacc[j] = (floatx4){0.f, 0.f, 0.f, 0.f};

        #pragma unroll
        for (int j = 0; j < 6; j++) {
            #pragma unroll
            for (int ks = 0; ks < 2; ks++) {
                half8 kf = *reinterpret_cast<const half8*>(Kc + (size_t)(j * 16 + ql) * HD + ks * 32 + g * 8);
                sacc[j] = __builtin_amdgcn_mfma_f32_16x16x32_f16(kf, qf[ks], sacc[j], 0, 0, 0);
            }
        }

        #pragma unroll
        for (int j = 0; j < 6; j++) {
            int hp = h_start + j;
            bool ok = fok && (hp - hq <= 2) && (hq - hp <= 2);
            half4 pv;
            #pragma unroll
            for (int r = 0; r < 4; r++) {
                float sv = (ok && wm[r]) ? sacc[j][r] : -10000.f;
                float p  = __builtin_amdgcn_exp2f(sv);
                lsum += p;
                pv[r] = (_Float16)p;
            }
            int byte = (ql * 640 + (fi * 96 + j * 16 + g * 4) * 2) ^ swz;
            *reinterpret_cast<half4*>(&P_lds[byte]) = pv;
        }
    }

    // row sums (q = ql lives in 4 lane-groups)
    lsum += __shfl_xor(lsum, 16);
    lsum += __shfl_xor(lsum, 32);
    float inv = __builtin_amdgcn_rcpf(lsum);

    __syncthreads();

    floatx4 oacc[4];
    #pragma unroll
    for (int dt = 0; dt < 4; dt++) oacc[dt] = (floatx4){0.f, 0.f, 0.f, 0.f};

    #pragma unroll
    for (int fi = 0; fi < 3; fi++) {
        int sbase = (f_start + fi) * 256 + h_start * 16;
        #pragma unroll
        for (int kw = 0; kw < 3; kw++) {
            int kcol = fi * 96 + kw * 32;
            int byte = (ql * 640 + (kcol + g * 8) * 2) ^ swz;
            half8 pa = *reinterpret_cast<half8*>(&P_lds[byte]);
            #pragma unroll
            for (int dt = 0; dt < 4; dt++) {
                half8 vf = *reinterpret_cast<const half8*>(
                    Vh + (size_t)(dt * 16 + ql) * SEQ + sbase + kw * 32 + g * 8);
                oacc[dt] = __builtin_amdgcn_mfma_f32_16x16x32_f16(pa, vf, oacc[dt], 0, 0, 0);
            }
        }
    }

    // epilogue: C row = q = g*4+rr, col = d = dt*16+ql; scale by 1/sum
    #pragma unroll
    for (int rr = 0; rr < 4; rr++) {
        float invr = __shfl(inv, g * 4 + rr);
        #pragma unroll
        for (int dt = 0; dt < 4; dt++) {
            AO[(size_t)(s0 + g * 4 + rr) * DIM + head * HD + dt * 16 + ql] =
                (_Float16)(oacc[dt][rr] * invr);
        }
    }
}

// ---------------- launch ----------------
extern "C" void kernel_launch(void* const* d_in, const int* in_sizes, int n_in,
                              void* d_out, int out_size, void* d_ws, size_t ws_size,
                              hipStream_t stream) {
    const float* H  = (const float*)d_in[0];
    const float* Wq = (const float*)d_in[1];
    const float* Wk = (const float*)d_in[2];
    const float* Wv = (const float*)d_in[3];
    const float* Wo = (const float*)d_in[4];
    const float* bo = (const float*)d_in[5];

    char* ws = (char*)d_ws;
    // layout: Hf16 [0,4M) | Wt x4 [4M,12M) | Q [12M,16M) | K [16M,20M) | Vt [20M,24M) | AO [24M,28M)
    _Float16* Hf = (_Float16*)(ws);
    _Float16* Wt = (_Float16*)(ws + (4u  << 20));
    _Float16* Qp = (_Float16*)(ws + (12u << 20));
    _Float16* Kp = (_Float16*)(ws + (16u << 20));
    _Float16* Vt = (_Float16*)(ws + (20u << 20));
    _Float16* AO = (_Float16*)(ws + (24u << 20));

    // 1. H -> f16
    cvt_f32_f16<<<(SEQ * DIM) / (256 * 4), 256, 0, stream>>>(H, Hf);

    // 2. weights -> transposed f16 (Wt[z][n][k] = W[k][n])
    transpose_cvt<<<dim3(32, 32, 4), dim3(32, 8), 0, stream>>>(Wq, Wk, Wv, Wo, Wt);

    // 3a. Q,K projections (per-head layout; Q pre-scaled)
    gemm128<0><<<dim3(16, 8, 2), 256, 0, stream>>>(Hf, Wt, Qp, nullptr, nullptr, DIM);

    // 3b. V^T = Wv^T * H^T  (M=1024 d-rows, N=2048 s-cols)
    gemm128<2><<<dim3(8, 16, 1), 256, 0, stream>>>(Wt + (size_t)2 * DIM * DIM, Hf, Vt,
                                                   nullptr, nullptr, SEQ);

    // 4. windowed MFMA attention: 2048 one-wave blocks
    attn_mfma<<<dim3(NHEAD * 128), 64, 0, stream>>>(Qp, Kp, Vt, AO);

    // 5. output projection + bias
    gemm128<1><<<dim3(16, 8, 1), 256, 0, stream>>>(AO, Wt + (size_t)3 * DIM * DIM, nullptr,
                                                   (float*)d_out, bo, DIM);
}

// Round 3
// 87.219 us; speedup vs baseline: 1.4845x; 1.2980x over previous
//
#include <hip/hip_runtime.h>
#include <hip/hip_bf16.h>
#include <hip/hip_fp16.h>

// ---------------- constants (problem is fixed-shape) ----------------
#define SEQ   2048
#define DIM   1024
#define NHEAD 16
#define HD    64
// grid (8,16,16), window (3,5,5) -> half windows 1,2,2
#define QSCALE 0.18033688011112042f   // (1/sqrt(64)) * log2(e), folded into Q

typedef _Float16 half8 __attribute__((ext_vector_type(8)));
typedef _Float16 half4 __attribute__((ext_vector_type(4)));
typedef float    floatx4 __attribute__((ext_vector_type(4)));

// async global->LDS, 16B per lane; LDS dest is wave-uniform base + lane*16
__device__ __forceinline__ void gload16(const void* g, void* l) {
    __builtin_amdgcn_global_load_lds(
        (const __attribute__((address_space(1))) unsigned int*)g,
        (__attribute__((address_space(3))) unsigned int*)l, 16, 0, 0);
}

// ---------------- 1. convert fp32 -> fp16 (vectorized) ----------------
__global__ void cvt_f32_f16(const float* __restrict__ in, _Float16* __restrict__ out) {
    int i = blockIdx.x * blockDim.x + threadIdx.x;
    int base = i * 4;
    float4 v = *reinterpret_cast<const float4*>(in + base);
    half4 o = { (_Float16)v.x, (_Float16)v.y, (_Float16)v.z, (_Float16)v.w };
    *reinterpret_cast<half4*>(out + base) = o;
}

// ---------------- 2. transpose + convert weights: T[n][k] = W[k][n] ----------------
__global__ void transpose_cvt(const float* __restrict__ W0, const float* __restrict__ W1,
                              const float* __restrict__ W2, const float* __restrict__ W3,
                              _Float16* __restrict__ T) {
    int z = blockIdx.z;
    const float* W = (z == 0) ? W0 : (z == 1) ? W1 : (z == 2) ? W2 : W3;
    _Float16* Tz = T + (size_t)z * (DIM * DIM);
    __shared__ float tile[32][33];
    int bx = blockIdx.x * 32;   // n-dim base
    int by = blockIdx.y * 32;   // k-dim base
    int tx = threadIdx.x, ty = threadIdx.y;
    #pragma unroll
    for (int i = 0; i < 32; i += 8)
        tile[ty + i][tx] = W[(size_t)(by + ty + i) * DIM + bx + tx];
    __syncthreads();
    #pragma unroll
    for (int i = 0; i < 32; i += 8)
        Tz[(size_t)(bx + ty + i) * DIM + by + tx] = (_Float16)tile[tx][ty + i];
}

// ---------------- GEMM core: 128x128 tile, BK=32, global_load_lds staging ----------------
// A_tile, B_tile: already offset to tile origin; both row-major with K-stride DIM.
// 256 threads = 4 waves (2x2); each wave 64x64 = 4x4 frags of mfma_f32_16x16x32_f16.
__device__ __forceinline__ void gemm_core(const _Float16* __restrict__ Ap,
                                          const _Float16* __restrict__ Bp,
                                          _Float16 (&As)[128][32], _Float16 (&Bs)[128][32],
                                          floatx4 (&acc)[4][4]) {
    int tid  = threadIdx.x;
    int lane = tid & 63;
    int wid  = tid >> 6;
    int wr = wid >> 1, wc = wid & 1;
    int r16 = lane & 15;
    int kk  = (lane >> 4) * 8;

    // staging map: linear LDS byte (tid + i*256)*16  <->  row=(tid>>2)+64i, col=(tid&3)*8
    int row0 = tid >> 2, col0 = (tid & 3) * 8;
    const _Float16* Ar = Ap + (size_t)row0 * DIM + col0;
    const _Float16* Br = Bp + (size_t)row0 * DIM + col0;
    char* AsW = (char*)&As[0][0] + wid * 1024;
    char* BsW = (char*)&Bs[0][0] + wid * 1024;

    for (int k0 = 0; k0 < DIM; k0 += 32) {
        gload16(Ar + k0,            AsW);
        gload16(Ar + 64 * DIM + k0, AsW + 4096);
        gload16(Br + k0,            BsW);
        gload16(Br + 64 * DIM + k0, BsW + 4096);
        __syncthreads();
        half8 a[4], b[4];
        #pragma unroll
        for (int m = 0; m < 4; m++) a[m] = *reinterpret_cast<half8*>(&As[wr * 64 + m * 16 + r16][kk]);
        #pragma unroll
        for (int n = 0; n < 4; n++) b[n] = *reinterpret_cast<half8*>(&Bs[wc * 64 + n * 16 + r16][kk]);
        #pragma unroll
        for (int m = 0; m < 4; m++)
            #pragma unroll
            for (int n = 0; n < 4; n++)
                acc[m][n] = __builtin_amdgcn_mfma_f32_16x16x32_f16(a[m], b[n], acc[m][n], 0, 0, 0);
        __syncthreads();
    }
}

// ---------------- 3. fused QKV projections ----------------
// z=0: Q = H*Wq^T (scaled, per-head layout)  z=1: K (per-head layout)
// z=2: V^T = Wv^T * H^T  (row-major [1024][2048]), tiles remapped from 16x8 grid
__global__ __launch_bounds__(256) void gemm_qkv(
        const _Float16* __restrict__ Hf, const _Float16* __restrict__ Wt,
        _Float16* __restrict__ Qp, _Float16* __restrict__ Kp, _Float16* __restrict__ Vt) {
    __shared__ _Float16 As[128][32];
    __shared__ _Float16 Bs[128][32];
    floatx4 acc[4][4] = {};

    int z = blockIdx.z;
    int tm, tn;
    const _Float16 *Ap, *Bp;
    if (z < 2) {
        tm = blockIdx.x; tn = blockIdx.y;
        Ap = Hf + (size_t)tm * 128 * DIM;
        Bp = Wt + (size_t)z * DIM * DIM + (size_t)tn * 128 * DIM;
    } else {
        tm = blockIdx.x & 7; tn = blockIdx.y * 2 + (blockIdx.x >> 3);
        Ap = Wt + (size_t)2 * DIM * DIM + (size_t)tm * 128 * DIM;
        Bp = Hf + (size_t)tn * 128 * DIM;
    }
    gemm_core(Ap, Bp, As, Bs, acc);

    int lane = threadIdx.x & 63, wid = threadIdx.x >> 6;
    int wr = wid >> 1, wc = wid & 1;
    float qs = (z == 0) ? QSCALE : 1.0f;
    _Float16* Oz = (z == 0) ? Qp : Kp;

    #pragma unroll
    for (int m = 0; m < 4; m++) {
        #pragma unroll
        for (int n = 0; n < 4; n++) {
            #pragma unroll
            for (int r = 0; r < 4; r++) {
                int row = tm * 128 + wr * 64 + m * 16 + (lane >> 4) * 4 + r;
                int col = tn * 128 + wc * 64 + n * 16 + (lane & 15);
                float v = acc[m][n][r];
                if (z < 2) {
                    int head = col >> 6;
                    Oz[(size_t)head * (SEQ * HD) + (size_t)row * HD + (col & 63)] = (_Float16)(v * qs);
                } else {
                    Vt[(size_t)row * SEQ + col] = (_Float16)v;
                }
            }
        }
    }
}

// ---------------- 5. output projection + bias ----------------
__global__ __launch_bounds__(256) void gemm_o(
        const _Float16* __restrict__ AO, const _Float16* __restrict__ WoT,
        const float* __restrict__ bias, float* __restrict__ out) {
    __shared__ _Float16 As[128][32];
    __shared__ _Float16 Bs[128][32];
    floatx4 acc[4][4] = {};

    int tm = blockIdx.x, tn = blockIdx.y;
    gemm_core(AO + (size_t)tm * 128 * DIM, WoT + (size_t)tn * 128 * DIM, As, Bs, acc);

    int lane = threadIdx.x & 63, wid = threadIdx.x >> 6;
    int wr = wid >> 1, wc = wid & 1;
    #pragma unroll
    for (int m = 0; m < 4; m++) {
        #pragma unroll
        for (int n = 0; n < 4; n++) {
            #pragma unroll
            for (int r = 0; r < 4; r++) {
                int row = tm * 128 + wr * 64 + m * 16 + (lane >> 4) * 4 + r;
                int col = tn * 128 + wc * 64 + n * 16 + (lane & 15);
                out[(size_t)row * DIM + col] = acc[m][n][r] + bias[col];
            }
        }
    }
}

// ---------------- 4. MFMA windowed attention: 1 wave per (head, f, h) row ----------------
// 16 queries (one w-row). Keys: 3 f-chunks x 6 h-rows x 16 w = 288, contiguous per chunk.
// Q pre-scaled by QSCALE at GEMM; softmax = exp2 with no max-sub; normalize at epilogue.
__global__ __launch_bounds__(256) void attn_mfma(
        const _Float16* __restrict__ Q,    // [16][2048][64] (scaled)
        const _Float16* __restrict__ K,    // [16][2048][64]
        const _Float16* __restrict__ Vt,   // [16][64][2048]
        _Float16* __restrict__ AO) {       // [2048][1024]
    __shared__ char P_lds[4][16 * 640];    // per-wave P[16 q][288 key] f16, XOR-swizzled

    int wid  = threadIdx.x >> 6;
    int lane = threadIdx.x & 63;
    int g    = lane >> 4;      // 0..3
    int ql   = lane & 15;

    int bid  = blockIdx.x * 4 + wid;
    int rid  = bid & 127;      // (f,h)
    int head = bid >> 7;
    int f    = rid >> 4;
    int hq   = rid & 15;
    int s0   = rid << 4;

    const _Float16* Qh = Q  + (size_t)head * (SEQ * HD);
    const _Float16* Kh = K  + (size_t)head * (SEQ * HD);
    const _Float16* Vh = Vt + (size_t)head * (HD * SEQ);

    int f_start = min(max(f - 1, 0), 5);
    int h_start = min(max(hq - 2, 0), 10);

    // per-lane w-mask: key w' = g*4+r, query w = ql
    bool wm[4];
    #pragma unroll
    for (int r = 0; r < 4; r++) {
        int wp = g * 4 + r;
        wm[r] = (wp - ql <= 2) && (ql - wp <= 2);
    }

    // Q B-frags (2 k-steps over d=64)
    half8 qf[2];
    #pragma unroll
    for (int ks = 0; ks < 2; ks++)
        qf[ks] = *reinterpret_cast<const half8*>(Qh + (size_t)(s0 + ql) * HD + ks * 32 + g * 8);

    float lsum = 0.f;
    int swz = (ql & 7) << 4;

    #pragma unroll
    for (int fi = 0; fi < 3; fi++) {
        int fp = f_start + fi;
        bool fok = (fp - f <= 1) && (f - fp <= 1);
        int sbase = fp * 256 + h_start * 16;
        const _Float16* Kc = Kh + (size_t)sbase * HD;

        floatx4 sacc[6];
        #pragma unroll
        for (int j = 0; j < 6; j++) sacc[j] = (floatx4){0.f, 0.f, 0.f, 0.f};

        #pragma unroll
        for (int j = 0; j < 6; j++) {
            #pragma unroll
            for (int ks = 0; ks < 2; ks++) {
                half8 kf = *reinterpret_cast<const half8*>(Kc + (size_t)(j * 16 + ql) * HD + ks * 32 + g * 8);
                sacc[j] = __builtin_amdgcn_mfma_f32_16x16x32_f16(kf, qf[ks], sacc[j], 0, 0, 0);
            }
        }

        #pragma unroll
        for (int j = 0; j < 6; j++) {
            int hp = h_start + j;
            bool ok = fok && (hp - hq <= 2) && (hq - hp <= 2);
            half4 pv;
            #pragma unroll
            for (int r = 0; r < 4; r++) {
                float sv = (ok && wm[r]) ? sacc[j][r] : -10000.f;
                float p  = __builtin_amdgcn_exp2f(sv);
                lsum += p;
                pv[r] = (_Float16)p;
            }
            int byte = (ql * 640 + (fi * 96 + j * 16 + g * 4) * 2) ^ swz;
            *reinterpret_cast<half4*>(&P_lds[wid][byte]) = pv;
        }
    }

    // row sums (q = ql lives in 4 lane-groups)
    lsum += __shfl_xor(lsum, 16);
    lsum += __shfl_xor(lsum, 32);
    float inv = __builtin_amdgcn_rcpf(lsum);

    __syncthreads();

    floatx4 oacc[4];
    #pragma unroll
    for (int dt = 0; dt < 4; dt++) oacc[dt] = (floatx4){0.f, 0.f, 0.f, 0.f};

    #pragma unroll
    for (int fi = 0; fi < 3; fi++) {
        int sbase = (f_start + fi) * 256 + h_start * 16;
        #pragma unroll
        for (int kw = 0; kw < 3; kw++) {
            int kcol = fi * 96 + kw * 32;
            int byte = (ql * 640 + (kcol + g * 8) * 2) ^ swz;
            half8 pa = *reinterpret_cast<half8*>(&P_lds[wid][byte]);
            #pragma unroll
            for (int dt = 0; dt < 4; dt++) {
                half8 vf = *reinterpret_cast<const half8*>(
                    Vh + (size_t)(dt * 16 + ql) * SEQ + sbase + kw * 32 + g * 8);
                oacc[dt] = __builtin_amdgcn_mfma_f32_16x16x32_f16(pa, vf, oacc[dt], 0, 0, 0);
            }
        }
    }

    // epilogue: C row = q = g*4+rr, col = d = dt*16+ql; scale by 1/sum
    #pragma unroll
    for (int rr = 0; rr < 4; rr++) {
        float invr = __shfl(inv, g * 4 + rr);
        #pragma unroll
        for (int dt = 0; dt < 4; dt++) {
            AO[(size_t)(s0 + g * 4 + rr) * DIM + head * HD + dt * 16 + ql] =
                (_Float16)(oacc[dt][rr] * invr);
        }
    }
}

// ---------------- launch ----------------
extern "C" void kernel_launch(void* const* d_in, const int* in_sizes, int n_in,
                              void* d_out, int out_size, void* d_ws, size_t ws_size,
                              hipStream_t stream) {
    const float* H  = (const float*)d_in[0];
    const float* Wq = (const float*)d_in[1];
    const float* Wk = (const float*)d_in[2];
    const float* Wv = (const float*)d_in[3];
    const float* Wo = (const float*)d_in[4];
    const float* bo = (const float*)d_in[5];

    char* ws = (char*)d_ws;
    // layout: Hf16 [0,4M) | Wt x4 [4M,12M) | Q [12M,16M) | K [16M,20M) | Vt [20M,24M) | AO [24M,28M)
    _Float16* Hf = (_Float16*)(ws);
    _Float16* Wt = (_Float16*)(ws + (4u  << 20));
    _Float16* Qp = (_Float16*)(ws + (12u << 20));
    _Float16* Kp = (_Float16*)(ws + (16u << 20));
    _Float16* Vt = (_Float16*)(ws + (20u << 20));
    _Float16* AO = (_Float16*)(ws + (24u << 20));

    // 1. H -> f16
    cvt_f32_f16<<<(SEQ * DIM) / (256 * 4), 256, 0, stream>>>(H, Hf);

    // 2. weights -> transposed f16 (Wt[z][n][k] = W[k][n])
    transpose_cvt<<<dim3(32, 32, 4), dim3(32, 8), 0, stream>>>(Wq, Wk, Wv, Wo, Wt);

    // 3. fused Q, K, V^T projections (z = 0,1: QK per-head; z = 2: V^T remapped)
    gemm_qkv<<<dim3(16, 8, 3), 256, 0, stream>>>(Hf, Wt, Qp, Kp, Vt);

    // 4. windowed MFMA attention: 2048 one-wave rows, 4 per block
    attn_mfma<<<dim3(NHEAD * 128 / 4), 256, 0, stream>>>(Qp, Kp, Vt, AO);

    // 5. output projection + bias
    gemm_o<<<dim3(16, 8), 256, 0, stream>>>(AO, Wt + (size_t)3 * DIM * DIM, bo, (float*)d_out);
}